// Round 3
// baseline (104.174 us; speedup 1.0000x reference)
//
#include <hip/hip_runtime.h>
#include <stdint.h>

#define NTOK 8192
#define NCOL 4096     // DIM == VOCAB
#define RANK 256
#define TPB  64       // tokens per block
#define CPB  512      // cols per block

typedef __attribute__((ext_vector_type(8))) short bf16x8;
typedef __attribute__((ext_vector_type(4))) float f32x4;

__device__ __forceinline__ unsigned short f2bf(float f) {
    unsigned int u = __float_as_uint(f);
    u += 0x7fffu + ((u >> 16) & 1u);   // RNE
    return (unsigned short)(u >> 16);
}

// ---- combined pre-pass ----
// blocks [0, 1024): A fp32 [4096][256] -> bf16 row-major  (4 elems/thread)
// blocks [1024, 1536): B fp32 [256][4096] -> bf16 MFMA-B-fragment order
//   frag layout: flat uint4 index = (ct*8 + ks)*64 + lane, 8 bf16 each:
//     element j = B[ks*32 + (lane>>4)*8 + j][ct*16 + (lane&15)]
__global__ __launch_bounds__(256) void prep_kernel(
    const float* __restrict__ A, const float* __restrict__ B,
    unsigned short* __restrict__ Abf, unsigned short* __restrict__ Bfrag)
{
    if (blockIdx.x < 1024) {
        int i = blockIdx.x * 256 + threadIdx.x;
        float4 v = reinterpret_cast<const float4*>(A)[i];
        ushort4 o;
        o.x = f2bf(v.x); o.y = f2bf(v.y); o.z = f2bf(v.z); o.w = f2bf(v.w);
        reinterpret_cast<ushort4*>(Abf)[i] = o;
    } else {
        int gt = (blockIdx.x - 1024) * 256 + threadIdx.x;   // 131072 threads
        int ct = gt >> 9;
        int rem = gt & 511;
        int ks = rem >> 6;
        int ln = rem & 63;
        int col = ct * 16 + (ln & 15);
        int kb  = ks * 32 + ((ln >> 4) << 3);
        unsigned short pk[8];
        #pragma unroll
        for (int j = 0; j < 8; ++j)
            pk[j] = f2bf(B[(size_t)(kb + j) * NCOL + col]);
        uint4 o;
        o.x = (unsigned)pk[0] | ((unsigned)pk[1] << 16);
        o.y = (unsigned)pk[2] | ((unsigned)pk[3] << 16);
        o.z = (unsigned)pk[4] | ((unsigned)pk[5] << 16);
        o.w = (unsigned)pk[6] | ((unsigned)pk[7] << 16);
        reinterpret_cast<uint4*>(Bfrag)[gt] = o;
    }
}

// ---- main: fused gather + LoRA GEMM + W add + mask, software-pipelined ----
__global__ __launch_bounds__(256, 4) void emb_lora_mfma(
    const int* __restrict__ x,
    const int* __restrict__ mask,
    const float* __restrict__ W,
    const unsigned short* __restrict__ Abf,
    const unsigned short* __restrict__ Bfrag,
    float* __restrict__ out)
{
    __shared__ unsigned short a_lds[TPB * RANK];     // 32 KB bf16
    __shared__ int s_idx[TPB];
    __shared__ int s_msk[TPB];

    const int tid  = threadIdx.x;
    const int lane = tid & 63;
    const int wave = tid >> 6;
    const int tok0 = blockIdx.x * TPB;
    const int col0 = blockIdx.y * CPB;

    if (tid < TPB) {
        s_idx[tid] = x[tok0 + tid];
        s_msk[tid] = mask[tok0 + tid];
    }
    __syncthreads();

    // stage 64 gathered A rows (bf16) into LDS
    #pragma unroll
    for (int it = 0; it < 8; ++it) {
        int c = it * 256 + tid;
        int row = c >> 5;
        int off = (c & 31) << 3;
        uint4 v = *reinterpret_cast<const uint4*>(
            Abf + (size_t)s_idx[row] * RANK + off);
        *reinterpret_cast<uint4*>(a_lds + row * RANK + off) = v;
    }
    __syncthreads();

    // per-wave A fragments (wave owns tokens [wave*16, wave*16+16))
    const int arow = wave * 16 + (lane & 15);
    const unsigned short* ap = a_lds + arow * RANK + ((lane >> 4) << 3);
    bf16x8 afrag[8];
    #pragma unroll
    for (int s = 0; s < 8; ++s)
        afrag[s] = *reinterpret_cast<const bf16x8*>(ap + s * 32);

    // hoisted epilogue state: this thread covers 4 consecutive token rows
    const int rowbase = wave * 16 + ((lane >> 4) << 2);
    int msk_r[4];
    const float* wptr[4];
    float* optr[4];
    #pragma unroll
    for (int r = 0; r < 4; ++r) {
        int row = rowbase + r;
        msk_r[r] = s_msk[row];
        wptr[r] = W + (size_t)s_idx[row] * NCOL + col0 + (lane & 15);
        optr[r] = out + (size_t)(tok0 + row) * NCOL + col0 + (lane & 15);
    }

    const uint4* bcol = reinterpret_cast<const uint4*>(Bfrag)
                        + (size_t)blockIdx.y * 32 * 512 + lane;

#define LOADB(bb, t)                                            \
    _Pragma("unroll")                                           \
    for (int s = 0; s < 8; ++s)                                 \
        bb[s] = bcol[(size_t)(t) * 512 + s * 64];

#define COMPUTE_STORE(bb, t)                                            \
    {                                                                   \
        float wv[4];                                                    \
        _Pragma("unroll")                                               \
        for (int r = 0; r < 4; ++r)                                     \
            wv[r] = msk_r[r] ? 0.0f : wptr[r][(t) * 16];                \
        f32x4 acc0 = {0.f,0.f,0.f,0.f}, acc1 = {0.f,0.f,0.f,0.f};       \
        _Pragma("unroll")                                               \
        for (int s = 0; s < 4; ++s) {                                   \
            acc0 = __builtin_amdgcn_mfma_f32_16x16x32_bf16(             \
                afrag[s], __builtin_bit_cast(bf16x8, bb[s]), acc0, 0, 0, 0); \
            acc1 = __builtin_amdgcn_mfma_f32_16x16x32_bf16(             \
                afrag[s + 4], __builtin_bit_cast(bf16x8, bb[s + 4]), acc1, 0, 0, 0); \
        }                                                               \
        _Pragma("unroll")                                               \
        for (int r = 0; r < 4; ++r) {                                   \
            float v = msk_r[r] ? 0.0f : (acc0[r] + acc1[r] + wv[r]);    \
            optr[r][(t) * 16] = v;                                      \
        }                                                               \
    }

    uint4 bA[8], bB[8];
    LOADB(bA, 0);
    #pragma unroll 1
    for (int t = 0; t < 32; t += 2) {
        LOADB(bB, t + 1);
        COMPUTE_STORE(bA, t);
        if (t + 2 < 32) { LOADB(bA, t + 2); }
        COMPUTE_STORE(bB, t + 1);
    }
#undef LOADB
#undef COMPUTE_STORE
}

extern "C" void kernel_launch(void* const* d_in, const int* in_sizes, int n_in,
                              void* d_out, int out_size, void* d_ws, size_t ws_size,
                              hipStream_t stream) {
    (void)in_sizes; (void)n_in; (void)out_size; (void)ws_size;

    const int*   x    = (const int*)d_in[0];
    const int*   mask = (const int*)d_in[1];
    const float* W    = (const float*)d_in[2];
    const float* A    = (const float*)d_in[3];
    const float* B    = (const float*)d_in[4];
    float*       out  = (float*)d_out;

    unsigned short* Abf   = (unsigned short*)d_ws;                       // 2 MiB
    unsigned short* Bfrag = (unsigned short*)((char*)d_ws + (2u << 20)); // 2 MiB

    prep_kernel<<<dim3(1536), dim3(256), 0, stream>>>(A, B, Abf, Bfrag);

    dim3 grid(NTOK / TPB, NCOL / CPB);   // (128, 8) = 1024 blocks
    emb_lora_mfma<<<grid, dim3(256), 0, stream>>>(x, mask, W, Abf, Bfrag, out);
}

// Round 4
// 70.622 us; speedup vs baseline: 1.4751x; 1.4751x over previous
//
#include <hip/hip_runtime.h>
#include <stdint.h>

#define NTOK 8192
#define NCOL 4096     // DIM == VOCAB
#define RANK 256
#define TPB  64       // tokens per block
#define CPB  512      // cols per block

typedef __attribute__((ext_vector_type(8))) short bf16x8;
typedef __attribute__((ext_vector_type(4))) float f32x4;

__device__ __forceinline__ unsigned short f2bf(float f) {
    unsigned int u = __float_as_uint(f);
    u += 0x7fffu + ((u >> 16) & 1u);   // RNE
    return (unsigned short)(u >> 16);
}

// ---- combined pre-pass ----
// blocks [0, 1024): A fp32 [4096][256] -> bf16 row-major
// blocks [1024, 1536): B fp32 [256][4096] -> bf16 MFMA-B-fragment order
//   frag layout: flat uint4 index = (ct*8 + ks)*64 + lane, 8 bf16 each:
//     element j = B[ks*32 + (lane>>4)*8 + j][ct*16 + (lane&15)]
__global__ __launch_bounds__(256) void prep_kernel(
    const float* __restrict__ A, const float* __restrict__ B,
    unsigned short* __restrict__ Abf, unsigned short* __restrict__ Bfrag)
{
    if (blockIdx.x < 1024) {
        int i = blockIdx.x * 256 + threadIdx.x;
        float4 v = reinterpret_cast<const float4*>(A)[i];
        ushort4 o;
        o.x = f2bf(v.x); o.y = f2bf(v.y); o.z = f2bf(v.z); o.w = f2bf(v.w);
        reinterpret_cast<ushort4*>(Abf)[i] = o;
    } else {
        int gt = (blockIdx.x - 1024) * 256 + threadIdx.x;
        int ct = gt >> 9;
        int rem = gt & 511;
        int ks = rem >> 6;
        int ln = rem & 63;
        int col = ct * 16 + (ln & 15);
        int kb  = ks * 32 + ((ln >> 4) << 3);
        unsigned short pk[8];
        #pragma unroll
        for (int j = 0; j < 8; ++j)
            pk[j] = f2bf(B[(size_t)(kb + j) * NCOL + col]);
        uint4 o;
        o.x = (unsigned)pk[0] | ((unsigned)pk[1] << 16);
        o.y = (unsigned)pk[2] | ((unsigned)pk[3] << 16);
        o.z = (unsigned)pk[4] | ((unsigned)pk[5] << 16);
        o.w = (unsigned)pk[6] | ((unsigned)pk[7] << 16);
        reinterpret_cast<uint4*>(Bfrag)[gt] = o;
    }
}

// ---- main: fused gather + LoRA GEMM + W add + mask ----
__global__ __launch_bounds__(256, 4) void emb_lora_mfma(
    const int* __restrict__ x,
    const int* __restrict__ mask,
    const float* __restrict__ W,
    const unsigned short* __restrict__ Abf,
    const unsigned short* __restrict__ Bfrag,
    float* __restrict__ out)
{
    __shared__ unsigned short a_lds[TPB * RANK];     // 32 KB bf16
    __shared__ int s_idx[TPB];
    __shared__ int s_msk[TPB];

    const int tid  = threadIdx.x;
    const int lane = tid & 63;
    const int wave = tid >> 6;
    const int tok0 = blockIdx.x * TPB;
    const int col0 = blockIdx.y * CPB;

    if (tid < TPB) {
        s_idx[tid] = x[tok0 + tid];
        s_msk[tid] = mask[tok0 + tid];
    }
    __syncthreads();

    // stage 64 gathered A rows (bf16) into LDS
    #pragma unroll
    for (int it = 0; it < 8; ++it) {
        int c = it * 256 + tid;
        int row = c >> 5;
        int off = (c & 31) << 3;
        uint4 v = *reinterpret_cast<const uint4*>(
            Abf + (size_t)s_idx[row] * RANK + off);
        *reinterpret_cast<uint4*>(a_lds + row * RANK + off) = v;
    }
    __syncthreads();

    // per-wave A fragments (wave owns tokens [wave*16, wave*16+16))
    const int arow = wave * 16 + (lane & 15);
    const unsigned short* ap = a_lds + arow * RANK + ((lane >> 4) << 3);
    bf16x8 afrag[8];
    #pragma unroll
    for (int s = 0; s < 8; ++s)
        afrag[s] = *reinterpret_cast<const bf16x8*>(ap + s * 32);

    // per-thread epilogue state: 4 consecutive token rows
    const int rowbase = wave * 16 + ((lane >> 4) << 2);
    int msk_r[4];
    const float* wptr[4];
    float* optr[4];
    #pragma unroll
    for (int r = 0; r < 4; ++r) {
        int row = rowbase + r;
        msk_r[r] = s_msk[row];
        wptr[r] = W + (size_t)s_idx[row] * NCOL + col0 + (lane & 15);
        optr[r] = out + (size_t)(tok0 + row) * NCOL + col0 + (lane & 15);
    }

    const uint4* bcol = reinterpret_cast<const uint4*>(Bfrag)
                        + (size_t)blockIdx.y * 32 * 512 + lane;

    // W prefetch ring, depth 4. Explicit `if` (NOT ternary) so the compiler
    // keeps the load exec-masked — masked lanes must not fetch (r3 lesson:
    // speculated loads doubled FETCH_SIZE).
    float wv[4][4];
    #pragma unroll
    for (int p = 0; p < 4; ++p) {
        #pragma unroll
        for (int r = 0; r < 4; ++r) {
            float v = 0.0f;
            if (!msk_r[r]) v = wptr[r][p * 16];
            wv[p][r] = v;
        }
    }

#define TILE_BODY(T, SLOT, PF)                                           \
    {                                                                    \
        const int t_ = (T);                                              \
        uint4 bb[8];                                                     \
        _Pragma("unroll")                                                \
        for (int s = 0; s < 8; ++s)                                      \
            bb[s] = bcol[t_ * 512 + s * 64];                             \
        float wcur[4];                                                   \
        _Pragma("unroll")                                                \
        for (int r = 0; r < 4; ++r) wcur[r] = wv[SLOT][r];               \
        if (PF) {                                                        \
            _Pragma("unroll")                                            \
            for (int r = 0; r < 4; ++r) {                                \
                float v = 0.0f;                                          \
                if (!msk_r[r]) v = wptr[r][(t_ + 4) * 16];               \
                wv[SLOT][r] = v;                                         \
            }                                                            \
        }                                                                \
        f32x4 acc0 = {0.f,0.f,0.f,0.f}, acc1 = {0.f,0.f,0.f,0.f};        \
        _Pragma("unroll")                                                \
        for (int s = 0; s < 4; ++s) {                                    \
            acc0 = __builtin_amdgcn_mfma_f32_16x16x32_bf16(              \
                afrag[s], __builtin_bit_cast(bf16x8, bb[s]), acc0, 0, 0, 0); \
            acc1 = __builtin_amdgcn_mfma_f32_16x16x32_bf16(              \
                afrag[s + 4], __builtin_bit_cast(bf16x8, bb[s + 4]), acc1, 0, 0, 0); \
        }                                                                \
        _Pragma("unroll")                                                \
        for (int r = 0; r < 4; ++r) {                                    \
            float v = msk_r[r] ? 0.0f : (acc0[r] + acc1[r] + wcur[r]);   \
            optr[r][t_ * 16] = v;                                        \
        }                                                                \
    }

    #pragma unroll 1
    for (int t0 = 0; t0 < 28; t0 += 4) {
        TILE_BODY(t0 + 0, 0, 1);
        TILE_BODY(t0 + 1, 1, 1);
        TILE_BODY(t0 + 2, 2, 1);
        TILE_BODY(t0 + 3, 3, 1);
    }
    // peeled tail: no prefetch (avoids OOB reads past W row end)
    TILE_BODY(28, 0, 0);
    TILE_BODY(29, 1, 0);
    TILE_BODY(30, 2, 0);
    TILE_BODY(31, 3, 0);
#undef TILE_BODY
}

extern "C" void kernel_launch(void* const* d_in, const int* in_sizes, int n_in,
                              void* d_out, int out_size, void* d_ws, size_t ws_size,
                              hipStream_t stream) {
    (void)in_sizes; (void)n_in; (void)out_size; (void)ws_size;

    const int*   x    = (const int*)d_in[0];
    const int*   mask = (const int*)d_in[1];
    const float* W    = (const float*)d_in[2];
    const float* A    = (const float*)d_in[3];
    const float* B    = (const float*)d_in[4];
    float*       out  = (float*)d_out;

    unsigned short* Abf   = (unsigned short*)d_ws;                       // 2 MiB
    unsigned short* Bfrag = (unsigned short*)((char*)d_ws + (2u << 20)); // 2 MiB

    prep_kernel<<<dim3(1536), dim3(256), 0, stream>>>(A, B, Abf, Bfrag);

    dim3 grid(NTOK / TPB, NCOL / CPB);   // (128, 8) = 1024 blocks
    emb_lora_mfma<<<grid, dim3(256), 0, stream>>>(x, mask, W, Abf, Bfrag, out);
}